// Round 12
// baseline (357.239 us; speedup 1.0000x reference)
//
#include <hip/hip_runtime.h>
#include <hip/hip_bf16.h>

// Problem: B=2, Ccat=128, OUT=64, H=W=256, f32 in/out storage, bf16-grade 2% tol.
// Pipeline (7 launches):
//   pre: MERGED {prep(weights+stats+halos) | xpose | upmfma} — mutually
//        independent, all pre-offconv; memory-bound + MFMA-bound blocks
//        co-resident (m114 overlap), 2 launch gaps removed.
//   offconv: R8 shape — 256px x 256oc, 512 thr / 8 waves, both-operands-in-LDS,
//            32 MFMA/barrier. PLATEAU (R9/R10): 128x128@3blk=91us,
//            128x256@2blk(256thr)=106us+spill. 83-87us shape is the optimum.
//   gather: bilinear deform -> PADDED xd (4 blocks/CU, 8-deep MLP)
//   conv1 = k_conv<128,0>: LDS implicit GEMM, 2-TAP pairing (32 MFMA/barrier,
//           R9 lesson), + bias + fused BN-stats
//   bnrelu1: BN(from raw sums)+ReLU -> PADDED h1
//   conv2 = k_conv<64,128>: same
//   bnrelu2: BN+ReLU + NHWC->NCHW f32 -> d_out
// Padded buffers: (B, 258, 264, C) bf16, data at [1..256][1..256], halos zeroed
// by pre -> conv staging needs no bounds checks.
// REGISTER BUDGET (R1/R3/R10): acc[8][4]=128 regs needs cap 256 AND the
// 512-thread shape (256-thread variants partially spill: +25MB WRITE).
// BARRIER-SPACING INVARIANT (R7): a gload_lds restage is visible to OTHER waves
// only after a __syncthreads() that FOLLOWS the issue. Ping-pong buffers.
// g_ws: xcat 0..36Mi | off 36..100Mi | xd(pad) 100..134Mi | c1o 134..150Mi |
//  h1(pad) 150..168Mi | c2o 168..184Mi | Wo/W1/W2 184Mi..+811008 | XPU 185..201Mi

typedef short short8 __attribute__((ext_vector_type(8)));
typedef short short4v __attribute__((ext_vector_type(4)));
typedef float f32x4 __attribute__((ext_vector_type(4)));

__device__ unsigned char g_ws[201u << 20] __attribute__((aligned(256)));
__device__ float g_st[256];

#define OFF_XCAT 0u
#define OFF_OFF  (36u << 20)
#define OFF_XD   (100u << 20)
#define OFF_C1O  (134u << 20)
#define OFF_H1   (150u << 20)
#define OFF_C2O  (168u << 20)
#define OFF_WO   (184u << 20)
#define OFF_W1   ((184u << 20) + 589824u)
#define OFF_W2   ((184u << 20) + 737280u)
#define OFF_XPU  (185u << 20)

// padded buffer geometry
#define XROW 264            // px per padded row
#define XRSH (XROW * 128)   // shorts per padded xcat row

__device__ __forceinline__ float b2f(__hip_bfloat16 v) { return __bfloat162float(v); }
__device__ __forceinline__ short f2b(float v) {
  __hip_bfloat16 h = __float2bfloat16(v); short s; __builtin_memcpy(&s, &h, 2); return s;
}
__device__ __forceinline__ float s2f(short s) {
  __hip_bfloat16 h; __builtin_memcpy(&h, &s, 2); return __bfloat162float(h);
}
__device__ __forceinline__ void gload_lds16(const void* g, void* l) {
  __builtin_amdgcn_global_load_lds(
      (const __attribute__((address_space(1))) void*)g,
      (__attribute__((address_space(3))) void*)l, 16, 0, 0);
}

// ---------- pre: MERGED prep | xpose | upmfma ----------
__device__ __forceinline__ void halo_zero(short* base, int C, int cshift, int u) {
  const int cg = u & ((1 << cshift) - 1);
  const int rest = u >> cshift;
  const int p = rest % 2576, b = rest / 2576;
  int row, col;
  if (p < 264) { row = 0; col = p; }
  else if (p < 528) { row = 257; col = p - 264; }
  else { int q = p - 528; row = 1 + (q >> 3); int cs = q & 7; col = cs ? 256 + cs : 0; }
  short8 z = {};
  *(short8*)(base + (((size_t)(b * 258) + row) * XROW + col) * C + cg * 8) = z;
}

// block ranges: [0,2389) prep | [2389,2901) xpose | [2901,3413) upmfma
// LDS: single 76544B buffer aliased (xpose T=36864B; upmfma W4|X|U|BS=76544B).
__global__ __launch_bounds__(256)
void k_pre(const float* __restrict__ offw, const float* __restrict__ c1w,
           const float* __restrict__ c2w, const float* __restrict__ x2,
           const float* __restrict__ x1, const float* __restrict__ up_w,
           const float* __restrict__ up_b) {
  __shared__ __align__(16) unsigned char SM[76544];
  const int bid = blockIdx.x;
  const int t = threadIdx.x;
  if (bid < 2389) {
    // ---- prep: weights + stats + halos ----
    const int fid = bid * 256 + t;
    if (bid == 0) g_st[t] = 0.f;
    __hip_bfloat16* Wo = (__hip_bfloat16*)(g_ws + OFF_WO);
    __hip_bfloat16* W1 = (__hip_bfloat16*)(g_ws + OFF_W1);
    __hip_bfloat16* W2 = (__hip_bfloat16*)(g_ws + OFF_W2);
    if (fid < 294912) {            // Wo: (tap*256+oc)*128+ic
      int ic = fid & 127, rest = fid >> 7, oc = rest & 255, tap = rest >> 8;
      Wo[fid] = __float2bfloat16(offw[(oc * 128 + ic) * 9 + tap]);
    } else if (fid < 368640) {     // W1: (tap*64+oc)*128+ic
      int l = fid - 294912;
      int ic = l & 127, rest = l >> 7, oc = rest & 63, tap = rest >> 6;
      W1[l] = __float2bfloat16(c1w[(oc * 128 + ic) * 9 + tap]);
    } else if (fid < 405504) {     // W2: (tap*64+oc)*64+ic
      int l = fid - 368640;
      int ic = l & 63, rest = l >> 6, oc = rest & 63, tap = rest >> 6;
      W2[l] = __float2bfloat16(c2w[(oc * 64 + ic) * 9 + tap]);
    } else {
      int u = fid - 405504;
      if (u < 82432) halo_zero((short*)(g_ws + OFF_XCAT), 128, 4, u);
      else if (u < 164864) halo_zero((short*)(g_ws + OFF_XD), 128, 4, u - 82432);
      else halo_zero((short*)(g_ws + OFF_H1), 64, 3, u - 164864);
    }
    return;
  }
  if (bid < 2901) {
    // ---- xpose: x2 NCHW f32 -> padded xcat NHWC bf16 lower 64ch ----
    short (*T)[72] = (short(*)[72])SM;   // 36864 B
    const int vb = bid - 2389;
    const int h = vb & 255, b = vb >> 8;
    const float* src = x2 + (size_t)(b * 64) * 65536 + h * 256;
    for (int rep = 0; rep < 64; ++rep) {
      int flat = rep * 256 + t, c = flat >> 8, w = flat & 255;
      T[w][c] = f2b(src[(size_t)c * 65536 + w]);
    }
    __syncthreads();
    short* xcat = (short*)(g_ws + OFF_XCAT) +
                  (((size_t)(b * 258) + h + 1) * XROW + 1) * 128;
    for (int rep = 0; rep < 8; ++rep) {
      int unit = rep * 256 + t;  // w*8+cg
      int w = unit >> 3, cg = unit & 7;
      *(short8*)(xcat + (size_t)w * 128 + cg * 8) = *(short8*)(&T[w][cg * 8]);
    }
    return;
  }
  // ---- upmfma: convT(2x2,s2) via 4 parity GEMMs -> xcat upper + XPU ----
  short (*W4)[64][66] = (short(*)[64][66])SM;                 // 33792 B
  short (*X)[68]      = (short(*)[68])(SM + 33792);           //  8704 B
  short (*U)[128][66] = (short(*)[128][66])(SM + 42496);      // 33792 B
  float* BS           = (float*)(SM + 76288);                 //   256 B
  const int vb = bid - 2901;
  const int half = vb & 1, hs = (vb >> 1) & 127, b = vb >> 8;
  for (int rep = 0; rep < 64; ++rep) {
    int flat = rep * 256 + t;
    int i = flat >> 8, rest = flat & 255, o = rest >> 2, kl = rest & 3;
    W4[kl][o][i] = f2b(up_w[flat]);
  }
  if (t < 64) BS[t] = up_b[t];
  const float* x1b = x1 + (size_t)(b * 64) * 16384 + hs * 128 + half * 64;
  for (int rep = 0; rep < 16; ++rep) {
    int flat = rep * 256 + t;
    int i = flat >> 6, ws = flat & 63;
    X[ws][i] = f2b(x1b[(size_t)i * 16384 + ws]);
  }
  __syncthreads();
  const int wv = t >> 6, lane = t & 63, l15 = lane & 15, quad = lane >> 4;
  short8 bf[2];
#pragma unroll
  for (int ks = 0; ks < 2; ++ks)
    bf[ks] = *(const short8*)(&X[wv * 16 + l15][ks * 32 + quad * 8]);
#pragma unroll
  for (int combo = 0; combo < 4; ++combo) {
    const int k = combo >> 1, l = combo & 1;
    f32x4 acc[4] = {};
#pragma unroll
    for (int nt = 0; nt < 4; ++nt)
#pragma unroll
      for (int ks = 0; ks < 2; ++ks) {
        short8 af = *(const short8*)(&W4[combo][nt * 16 + l15][ks * 32 + quad * 8]);
        acc[nt] = __builtin_amdgcn_mfma_f32_16x16x32_bf16(af, bf[ks], acc[nt], 0, 0, 0);
      }
    const int wl = 2 * (wv * 16 + l15) + l;
#pragma unroll
    for (int nt = 0; nt < 4; ++nt) {
      short4v s;
#pragma unroll
      for (int r = 0; r < 4; ++r) s[r] = f2b(acc[nt][r] + BS[nt * 16 + quad * 4 + r]);
      *(short4v*)(&U[k][wl][nt * 16 + quad * 4]) = s;
    }
  }
  __syncthreads();
  short* xcat = (short*)(g_ws + OFF_XCAT);
  short* xpu = (short*)(g_ws + OFF_XPU);
  for (int rep = 0; rep < 8; ++rep) {
    int unit = rep * 256 + t;
    int k = unit >> 10, wl = (unit >> 3) & 127, cg = unit & 7;
    int h = 2 * hs + k, w = half * 128 + wl;
    *(short8*)(xcat + (((size_t)(b * 258) + h + 1) * XROW + w + 1) * 128 + 64 + cg * 8) =
        *(short8*)(&U[k][wl][cg * 8]);
  }
  for (int rep = 0; rep < 8; ++rep) {
    int unit = rep * 256 + t;
    int o = unit >> 5, k = (unit >> 4) & 1, wg = unit & 15;
    int h = 2 * hs + k;
    short8 v;
#pragma unroll
    for (int j = 0; j < 8; ++j) v[j] = U[k][wg * 8 + j][o];
    *(short8*)(xpu + (size_t)(b * 64 + o) * 65536 + h * 256 + half * 128 + wg * 8) = v;
  }
}

// ---------- offconv: BOTH-operands-in-LDS implicit GEMM, 256px x 256oc (R8/R11, 83us) ----------
__global__ __launch_bounds__(512, 2)
void k_offconv() {
  __shared__ short Bs[3 * 264 * 64];   // 101376 B
  __shared__ short As0[256 * 32];      // 16384 B
  __shared__ short As1[256 * 32];      // 16384 B
  const short* X = (const short*)(g_ws + OFF_XCAT);
  const __hip_bfloat16* W = (const __hip_bfloat16*)(g_ws + OFF_WO);
  const int t = threadIdx.x;
  const int vb = (int)((blockIdx.x & 7) * 64 + (blockIdx.x >> 3));  // bijective, 512%8==0
  const int h = vb & 255, b = vb >> 8;
  const int wid = t >> 6, lane = t & 63, l15 = lane & 15, quad = lane >> 4;
  const int ocbase = (wid & 1) * 128;
  const int pxb = (wid >> 1) * 64;
  const int lpx = lane >> 3, lcg = lane & 7;
  const short* bsrc = X + (((size_t)(b * 258) + h) * XROW + lpx) * 128 + (lcg ^ (lpx & 7)) * 8;
  const int loc = lane >> 2, lcg4 = lane & 3;
  const __hip_bfloat16* asrc = W + (size_t)loc * 128 + (lcg4 ^ ((loc + (loc >> 2)) & 3)) * 8;
  const int ax = (quad ^ ((l15 + (l15 >> 2)) & 3)) << 3;  // shorts
  const int abase = (ocbase + l15) * 32 + ax;
  f32x4 acc[8][4] = {};

#define STAGE_A(TAP, ICS, P, APTR)                                                  \
  {                                                                                 \
    _Pragma("unroll")                                                               \
    for (int k = 0; k < 2; ++k) {                                                   \
      int u = wid * 2 + k;                                                          \
      gload_lds16(asrc + ((size_t)(TAP) * 256 + u * 16) * 128 + (P) * 64 + (ICS) * 32, \
                  &APTR[u * 512]);                                                  \
    }                                                                               \
  }

  for (int p = 0; p < 2; ++p) {
    if (p) __syncthreads();
    for (int u = wid; u < 99; u += 8) {
      int r = u / 33, g = u - r * 33;
      gload_lds16(bsrc + (size_t)r * XRSH + g * 1024 + p * 64, &Bs[(r * 264 + g * 8) * 64]);
    }
    STAGE_A(0, 0, p, As0);
    STAGE_A(0, 1, p, As1);
    __syncthreads();
    for (int tap = 0; tap < 9; ++tap) {
      const int ky = tap / 3, kx = tap - 3 * ky;
      const short* srow = &Bs[(ky * 264 + pxb + l15 + kx) * 64];
      const int sx = ((l15 + kx) & 7) << 3;
      {  // ics = 0
        short8 a[8], bf[4];
#pragma unroll
        for (int ot = 0; ot < 8; ++ot) a[ot] = *(const short8*)(As0 + abase + ot * 512);
#pragma unroll
        for (int pt = 0; pt < 4; ++pt)
          bf[pt] = *(const short8*)(srow + pt * 1024 + ((quad * 8) ^ sx));
        __syncthreads();
        if (tap < 8) STAGE_A(tap + 1, 0, p, As0);
#pragma unroll
        for (int ot = 0; ot < 8; ++ot)
#pragma unroll
          for (int pt = 0; pt < 4; ++pt)
            acc[ot][pt] = __builtin_amdgcn_mfma_f32_16x16x32_bf16(a[ot], bf[pt], acc[ot][pt], 0, 0, 0);
      }
      {  // ics = 1
        short8 a[8], bf[4];
#pragma unroll
        for (int ot = 0; ot < 8; ++ot) a[ot] = *(const short8*)(As1 + abase + ot * 512);
#pragma unroll
        for (int pt = 0; pt < 4; ++pt)
          bf[pt] = *(const short8*)(srow + pt * 1024 + ((32 + quad * 8) ^ sx));
        __syncthreads();
        if (tap < 8) STAGE_A(tap + 1, 1, p, As1);
#pragma unroll
        for (int ot = 0; ot < 8; ++ot)
#pragma unroll
          for (int pt = 0; pt < 4; ++pt)
            acc[ot][pt] = __builtin_amdgcn_mfma_f32_16x16x32_bf16(a[ot], bf[pt], acc[ot][pt], 0, 0, 0);
      }
    }
  }
  __hip_bfloat16* out = (__hip_bfloat16*)(g_ws + OFF_OFF);  // NCHW (B,256,256,256)
#pragma unroll
  for (int ot = 0; ot < 8; ++ot)
#pragma unroll
    for (int pt = 0; pt < 4; ++pt)
#pragma unroll
      for (int r = 0; r < 4; ++r) {
        int oc = ocbase + ot * 16 + quad * 4 + r;
        int px = pxb + pt * 16 + l15;
        out[(((size_t)(b * 256 + oc)) * 256 + h) * 256 + px] =
            __float2bfloat16(acc[ot][pt][r]);
      }
#undef STAGE_A
}

// ---------- k_conv: LDS implicit-GEMM 3x3 conv (OC=64), 2-TAP pairing, + bias + stats ----------
// Per barrier interval (R9 lesson: 32 MFMA/barrier): stage next TAP PAIR into
// idle ping-pong buffer -> read 2 taps' A+B -> 32 MFMA -> barrier.
// Pairs: {0,1}{2,3}{4,5}{6,7}{8}. As buffers 2x4096 shorts (2 taps each).
// LDS 69.1KB -> 2 blocks/CU. R7 invariant holds (stage before barrier, reads
// of that buffer only after it).
template <int IC, int SO>
__global__ __launch_bounds__(256, 2)
void k_conv(size_t xoff, size_t woff, const float* __restrict__ bias, size_t ooff) {
  __shared__ short Bs[3 * 272 * 32];   // 52224 B
  __shared__ short As[2][4096];        // 16384 B (each: 2 taps x 64oc x 32ch)
  __shared__ float SB[128];
  const short* X = (const short*)(g_ws + xoff);
  const __hip_bfloat16* W = (const __hip_bfloat16*)(g_ws + woff);
  const int t = threadIdx.x;
  const int vb = (int)((blockIdx.x & 7) * 64 + (blockIdx.x >> 3));  // bijective, 512%8==0
  const int h = vb & 255, b = vb >> 8;
  const int wid = t >> 6, lane = t & 63, l15 = lane & 15, quad = lane >> 4;
  const int pxb = wid * 64;
  if (t < 128) SB[t] = 0.f;
  const int lpx = lane >> 2, lc = lane & 3;
  const int fl = (lpx + (lpx >> 2)) & 3;
  const short* bsrc = X + (((size_t)(b * 258) + h) * XROW + lpx) * IC + (lc ^ fl) * 8;
  const __hip_bfloat16* asrc = W + (size_t)lpx * IC + (lc ^ fl) * 8;
  const int aslot = (quad ^ ((l15 + (l15 >> 2)) & 3)) << 3;  // shorts
  f32x4 acc[4][4] = {};
  const int KP = IC / 32;
  for (int ph = 0; ph < KP; ++ph) {
    for (int u = wid; u < 51; u += 4) {      // B: 3 rows x 17 units of 16px x 32ch
      int r = u / 17, g = u - r * 17;
      gload_lds16(bsrc + ((size_t)r * XROW + g * 16) * IC + ph * 32,
                  &Bs[(r * 272 + g * 16) * 32]);
    }
#pragma unroll
    for (int k = 0; k < 2; ++k) {            // pair {0,1} -> As[0]: 8 units of 16oc
      int u = wid * 2 + k;                   // u: tap=(u>>2), ocu=(u&3)
      gload_lds16(asrc + ((size_t)((u >> 2) * 64 + (u & 3) * 16)) * IC + ph * 32,
                  &As[0][u * 512]);
    }
    __syncthreads();          // own vmcnt drained -> Bs + As[0] ready for all
    for (int pr = 0; pr < 5; ++pr) {
      const short* cur = As[pr & 1];
      short* nxt = As[(pr & 1) ^ 1];
      if (pr < 4) {           // stage next pair (taps 2pr+2[,2pr+3]) into idle buf
        const int bt = 2 * pr + 2;
        const int nunits = (bt == 8) ? 4 : 8;
#pragma unroll
        for (int k = 0; k < 2; ++k) {
          int u = wid * 2 + k;
          if (u < nunits)
            gload_lds16(asrc + ((size_t)((bt + (u >> 2)) * 64 + (u & 3) * 16)) * IC + ph * 32,
                        &nxt[u * 512]);
        }
      }
      const int ntap = (pr == 4) ? 1 : 2;
      for (int tt = 0; tt < ntap; ++tt) {
        const int tap = 2 * pr + tt;
        const int ky = tap / 3, kx = tap - 3 * ky;
        short8 a[4], bf[4];
#pragma unroll
        for (int ot = 0; ot < 4; ++ot)
          a[ot] = *(const short8*)(&cur[tt * 2048 + (ot * 16 + l15) * 32 + aslot]);
        const int s = l15 + kx;
        const int bslot = (quad ^ ((s + (s >> 2)) & 3)) << 3;
#pragma unroll
        for (int pt = 0; pt < 4; ++pt)
          bf[pt] = *(const short8*)(&Bs[(ky * 272 + pxb + pt * 16 + s) * 32 + bslot]);
#pragma unroll
        for (int ot = 0; ot < 4; ++ot)
#pragma unroll
          for (int pt = 0; pt < 4; ++pt)
            acc[ot][pt] = __builtin_amdgcn_mfma_f32_16x16x32_bf16(a[ot], bf[pt], acc[ot][pt], 0, 0, 0);
      }
      __syncthreads();        // own restage drained -> nxt ready for ALL waves
    }
  }
  // epilogue: bias + store NHWC + fused stats
  __hip_bfloat16* out = (__hip_bfloat16*)(g_ws + ooff);
#pragma unroll
  for (int ot = 0; ot < 4; ++ot) {
    const int oc0 = ot * 16 + quad * 4;
    float bv[4], sa[4] = {}, sa2[4] = {};
#pragma unroll
    for (int r = 0; r < 4; ++r) bv[r] = bias[oc0 + r];
#pragma unroll
    for (int pt = 0; pt < 4; ++pt) {
      const int px = pxb + pt * 16 + l15;
      short4v sv;
#pragma unroll
      for (int r = 0; r < 4; ++r) {
        float f = acc[ot][pt][r] + bv[r];
        sv[r] = f2b(f);
        sa[r] += f;
        sa2[r] = fmaf(f, f, sa2[r]);
      }
      *(short4v*)(out + ((((size_t)(b * 256) + h) * 256 + px) * 64 + oc0)) = sv;
    }
#pragma unroll
    for (int r = 0; r < 4; ++r) {
      float sv1 = sa[r], sv2 = sa2[r];
      for (int d = 1; d < 16; d <<= 1) {
        sv1 += __shfl_xor(sv1, d);
        sv2 += __shfl_xor(sv2, d);
      }
      if (l15 == 0) {
        atomicAdd(&SB[oc0 + r], sv1);
        atomicAdd(&SB[64 + oc0 + r], sv2);
      }
    }
  }
  __syncthreads();
  if (t < 128) atomicAdd(&g_st[SO + t], SB[t]);
}

// ---------- deform gather: channel-half per block, 8-deep offset pipeline -> PADDED xd ----------
__global__ __launch_bounds__(256, 4)
void k_gather(const float* __restrict__ x2) {
  __shared__ short G[256 * 66];   // 33792 B
  const __hip_bfloat16* off = (const __hip_bfloat16*)(g_ws + OFF_OFF);
  const __hip_bfloat16* xpu = (const __hip_bfloat16*)(g_ws + OFF_XPU);
  short* xd = (short*)(g_ws + OFF_XD);
  const int t = threadIdx.x;
  const int half = blockIdx.x & 1;
  const int hh = (blockIdx.x >> 1) & 255, b = blockIdx.x >> 9;
  const int hp = 2 * (hh & 127) + (t >> 7);
  const int w0e = 2 * (t & 127);
  const int chb = hh >> 7;
  const int c0 = half * 64;
  const float fh = (float)hh, fw = (float)t;
  const __hip_bfloat16* offb = off + ((size_t)(b * 256) * 256 + hp) * 256 + w0e +
                               (size_t)(2 * c0 + chb) * 65536;
  if (half == 0) {
    const float* x2b = x2 + (size_t)b * 64 * 65536;
    for (int g8 = 0; g8 < 8; ++g8) {
      unsigned ovv[8];
#pragma unroll
      for (int j = 0; j < 8; ++j)
        ovv[j] = *(const unsigned*)(offb + (size_t)(2 * (g8 * 8 + j)) * 65536);
#pragma unroll
      for (int j = 0; j < 8; ++j) {
        const int crel = g8 * 8 + j;
        unsigned ov = ovv[j];
        float oy = __uint_as_float((ov & 0xffffu) << 16);
        float ox = __uint_as_float((ov >> 16) << 16);
        float cy = fminf(fmaxf(oy + fh, 0.f), 255.f);
        float cx = fminf(fmaxf(ox + fw, 0.f), 255.f);
        float y0f = floorf(cy), x0f = floorf(cx);
        int y0 = (int)y0f, x0 = (int)x0f;
        int y1 = (int)ceilf(cy), x1 = (int)ceilf(cx);
        const float* pl = x2b + (size_t)crel * 65536;
        float v00 = pl[y0 * 256 + x0], v10 = pl[y1 * 256 + x0];
        float v01 = pl[y0 * 256 + x1], v11 = pl[y1 * 256 + x1];
        float wy = cy - y0f, wx = cx - x0f;
        float vt = v00 + (v10 - v00) * wy;
        float vb = v01 + (v11 - v01) * wy;
        G[t * 66 + crel] = f2b(vt + (vb - vt) * wx);
      }
    }
  } else {
    const __hip_bfloat16* xub = xpu + (size_t)b * 64 * 65536;
    for (int g8 = 0; g8 < 8; ++g8) {
      unsigned ovv[8];
#pragma unroll
      for (int j = 0; j < 8; ++j)
        ovv[j] = *(const unsigned*)(offb + (size_t)(2 * (g8 * 8 + j)) * 65536);
#pragma unroll
      for (int j = 0; j < 8; ++j) {
        const int crel = g8 * 8 + j;
        unsigned ov = ovv[j];
        float oy = __uint_as_float((ov & 0xffffu) << 16);
        float ox = __uint_as_float((ov >> 16) << 16);
        float cy = fminf(fmaxf(oy + fh, 0.f), 255.f);
        float cx = fminf(fmaxf(ox + fw, 0.f), 255.f);
        float y0f = floorf(cy), x0f = floorf(cx);
        int y0 = (int)y0f, x0 = (int)x0f;
        int y1 = (int)ceilf(cy), x1 = (int)ceilf(cx);
        const __hip_bfloat16* pl = xub + (size_t)crel * 65536;
        float v00 = b2f(pl[y0 * 256 + x0]), v10 = b2f(pl[y1 * 256 + x0]);
        float v01 = b2f(pl[y0 * 256 + x1]), v11 = b2f(pl[y1 * 256 + x1]);
        float wy = cy - y0f, wx = cx - x0f;
        float vt = v00 + (v10 - v00) * wy;
        float vb = v01 + (v11 - v01) * wy;
        G[t * 66 + crel] = f2b(vt + (vb - vt) * wx);
      }
    }
  }
  __syncthreads();
  const size_t dst = (((size_t)(b * 258) + hh + 1) * XROW + 1) * 128 + c0;
  for (int it = 0; it < 8; ++it) {
    int g = it * 256 + t;
    *(short8*)(xd + dst + (size_t)(g >> 3) * 128 + (g & 7) * 8) =
        *(short8*)(&G[(g >> 3) * 66 + (g & 7) * 8]);
  }
}

// ---------- BN apply + ReLU: c1o NHWC -> PADDED h1 NHWC bf16 (finstat folded) ----------
__global__ __launch_bounds__(256)
void k_bnrelu1(const float* __restrict__ g, const float* __restrict__ be) {
  __shared__ float A[64], Bc[64];
  const __hip_bfloat16* x = (const __hip_bfloat16*)(g_ws + OFF_C1O);
  short* o = (short*)(g_ws + OFF_H1);
  const int t = threadIdx.x;
  const int h = blockIdx.x & 255, b = blockIdx.x >> 8;
  if (t < 64) {
    float m = g_st[t] * (1.f / 131072.f);
    float v = g_st[64 + t] * (1.f / 131072.f) - m * m;
    float iv = rsqrtf(v + 1e-5f) * g[t];
    A[t] = iv;
    Bc[t] = be[t] - m * iv;
  }
  __syncthreads();
  const __hip_bfloat16* px = x + (((size_t)(b * 256) + h) * 256 + t) * 64;
  short* op = o + (((size_t)(b * 258) + h + 1) * XROW + t + 1) * 64;
#pragma unroll
  for (int cg = 0; cg < 8; ++cg) {
    short8 v = *(const short8*)(px + cg * 8);
    short8 r;
#pragma unroll
    for (int j = 0; j < 8; ++j) {
      int c = cg * 8 + j;
      r[j] = f2b(fmaxf(s2f(v[j]) * A[c] + Bc[c], 0.f));
    }
    *(short8*)(op + cg * 8) = r;
  }
}

// ---------- BN apply + ReLU + NHWC->NCHW f32 to d_out (finstat folded) ----------
__global__ __launch_bounds__(256)
void k_bnrelu2(const float* __restrict__ g, const float* __restrict__ be,
               float* __restrict__ dout) {
  __shared__ float T[64 * 257];
  __shared__ float A[64], Bc[64];
  const __hip_bfloat16* x = (const __hip_bfloat16*)(g_ws + OFF_C2O);
  const int t = threadIdx.x;
  const int h = blockIdx.x & 255, b = blockIdx.x >> 8;
  if (t < 64) {
    float m = g_st[128 + t] * (1.f / 131072.f);
    float v = g_st[192 + t] * (1.f / 131072.f) - m * m;
    float iv = rsqrtf(v + 1e-5f) * g[t];
    A[t] = iv;
    Bc[t] = be[t] - m * iv;
  }
  __syncthreads();
  const __hip_bfloat16* px = x + (((size_t)(b * 256) + h) * 256 + t) * 64;
#pragma unroll
  for (int cg = 0; cg < 8; ++cg) {
    short8 v = *(const short8*)(px + cg * 8);
#pragma unroll
    for (int j = 0; j < 8; ++j) {
      int c = cg * 8 + j;
      T[c * 257 + t] = fmaxf(s2f(v[j]) * A[c] + Bc[c], 0.f);
    }
  }
  __syncthreads();
  for (int rep = 0; rep < 64; ++rep) {
    int flat = rep * 256 + t, c = flat >> 8, w = flat & 255;
    dout[(((size_t)(b * 64 + c)) * 256 + h) * 256 + w] = T[c * 257 + w];
  }
}

extern "C" void kernel_launch(void* const* d_in, const int* in_sizes, int n_in,
                              void* d_out, int out_size, void* d_ws, size_t ws_size,
                              hipStream_t stream) {
  const bool ok = (n_in == 13) &&
                  in_sizes[0] == 2097152 && in_sizes[1] == 8388608 &&
                  in_sizes[2] == 16384 && in_sizes[3] == 64 &&
                  in_sizes[4] == 294912 && in_sizes[5] == 73728 &&
                  in_sizes[9] == 36864 && out_size == 8388608;
  if (!ok) { hipMemsetAsync(d_out, 0x46, (size_t)out_size * 2, stream); return; }

  const float* x1   = (const float*)d_in[0];
  const float* x2   = (const float*)d_in[1];
  const float* up_w = (const float*)d_in[2];
  const float* up_b = (const float*)d_in[3];
  const float* offw = (const float*)d_in[4];
  const float* c1w  = (const float*)d_in[5];
  const float* c1b  = (const float*)d_in[6];
  const float* g1   = (const float*)d_in[7];
  const float* b1   = (const float*)d_in[8];
  const float* c2w  = (const float*)d_in[9];
  const float* c2b  = (const float*)d_in[10];
  const float* g2   = (const float*)d_in[11];
  const float* b2   = (const float*)d_in[12];

  k_pre<<<3413, 256, 0, stream>>>(offw, c1w, c2w, x2, x1, up_w, up_b);
  k_offconv<<<512, 512, 0, stream>>>();
  k_gather<<<1024, 256, 0, stream>>>(x2);
  k_conv<128, 0><<<512, 256, 0, stream>>>(OFF_XD, OFF_W1, c1b, OFF_C1O);
  k_bnrelu1<<<512, 256, 0, stream>>>(g1, b1);
  k_conv<64, 128><<<512, 256, 0, stream>>>(OFF_H1, OFF_W2, c2b, OFF_C2O);
  k_bnrelu2<<<512, 256, 0, stream>>>(g2, b2, (float*)d_out);

  (void)d_ws; (void)ws_size;
}

// Round 13
// 341.895 us; speedup vs baseline: 1.0449x; 1.0449x over previous
//
#include <hip/hip_runtime.h>
#include <hip/hip_bf16.h>

// Problem: B=2, Ccat=128, OUT=64, H=W=256, f32 in/out storage, bf16-grade 2% tol.
// Pipeline (9 launches) — R8 configuration, measured best (339.4 us):
//   prep: weights -> [tap][oc][ic] bf16; zero stats; zero ALL padded halos
//   xpose: x2 NCHW -> padded xcat NHWC lower 64ch
//   upmfma: convT2x2 (MFMA, 4 parity GEMMs) -> padded xcat upper 64ch + planar XPU
//   offconv: both-operands-in-LDS implicit GEMM 128->256, 256px x 256oc,
//            512 thr / 8 waves, 32 MFMA/barrier (~87us, MfmaUtil ~38%)
//   gather: bilinear deform -> PADDED xd NHWC bf16 (4 blocks/CU, 4-deep MLP)
//   conv1 = k_conv<128,0>: LDS-staged implicit GEMM + bias + FUSED BN-stats
//   bnrelu1: BN(from raw sums)+ReLU -> PADDED h1
//   conv2 = k_conv<64,128>: same + fused stats
//   bnrelu2: BN+ReLU + NHWC->NCHW f32 -> d_out
// SESSION LESSONS (R9-R12, all falsified alternatives):
//   - offconv reshape: 128x128@3blk=91us; 128x256@2blk(256thr)=106us(+spill);
//     this 256x256@512thr shape is the plateau optimum.
//   - gather 8-deep MLP: neutral-to-negative vs 4-deep.
//   - merging prep/xpose/upmfma into one launch: REGRESSION — the launch gaps
//     drain ~70MB of dirty L2 (xcat+XPU) before offconv; merged, that
//     writeback lands inside offconv's window (83->103us, WRITE +8MB).
// Padded buffers: (B, 258 rows, 264 px, C) bf16, data at [1..256][1..256],
// halos zeroed once by prep -> conv staging needs no bounds checks.
// REGISTER BUDGET (R1/R3/R10): acc[8][4]=128 regs needs cap 256 AND the
// 512-thread shape (256-thread variants partially spill: +25MB WRITE).
// BARRIER-SPACING INVARIANT (R7): a gload_lds restage is visible to OTHER waves
// only after a __syncthreads() that FOLLOWS the issue. Ping-pong As, 1 barrier/tap.
// g_ws: xcat 0..36Mi | off 36..100Mi | xd(pad) 100..134Mi | c1o 134..150Mi |
//  h1(pad) 150..168Mi | c2o 168..184Mi | Wo/W1/W2 184Mi..+811008 | XPU 185..201Mi

typedef short short8 __attribute__((ext_vector_type(8)));
typedef short short4v __attribute__((ext_vector_type(4)));
typedef float f32x4 __attribute__((ext_vector_type(4)));

__device__ unsigned char g_ws[201u << 20] __attribute__((aligned(256)));
__device__ float g_st[256];

#define OFF_XCAT 0u
#define OFF_OFF  (36u << 20)
#define OFF_XD   (100u << 20)
#define OFF_C1O  (134u << 20)
#define OFF_H1   (150u << 20)
#define OFF_C2O  (168u << 20)
#define OFF_WO   (184u << 20)
#define OFF_W1   ((184u << 20) + 589824u)
#define OFF_W2   ((184u << 20) + 737280u)
#define OFF_XPU  (185u << 20)

// padded buffer geometry
#define XROW 264            // px per padded row
#define XRSH (XROW * 128)   // shorts per padded xcat row

__device__ __forceinline__ float b2f(__hip_bfloat16 v) { return __bfloat162float(v); }
__device__ __forceinline__ short f2b(float v) {
  __hip_bfloat16 h = __float2bfloat16(v); short s; __builtin_memcpy(&s, &h, 2); return s;
}
__device__ __forceinline__ float s2f(short s) {
  __hip_bfloat16 h; __builtin_memcpy(&h, &s, 2); return __bfloat162float(h);
}
__device__ __forceinline__ void gload_lds16(const void* g, void* l) {
  __builtin_amdgcn_global_load_lds(
      (const __attribute__((address_space(1))) void*)g,
      (__attribute__((address_space(3))) void*)l, 16, 0, 0);
}

// ---------- prep: weight transforms + zero stats + zero padded halos ----------
// unit map: [0,405504) weights | then xcat halo (82432) | xd halo (82432) |
// h1 halo (41216). total 611584 = 2389 * 256.
__device__ __forceinline__ void halo_zero(short* base, int C, int cshift, int u) {
  const int cg = u & ((1 << cshift) - 1);
  const int rest = u >> cshift;
  const int p = rest % 2576, b = rest / 2576;
  int row, col;
  if (p < 264) { row = 0; col = p; }
  else if (p < 528) { row = 257; col = p - 264; }
  else { int q = p - 528; row = 1 + (q >> 3); int cs = q & 7; col = cs ? 256 + cs : 0; }
  short8 z = {};
  *(short8*)(base + (((size_t)(b * 258) + row) * XROW + col) * C + cg * 8) = z;
}

__global__ __launch_bounds__(256)
void k_prep(const float* __restrict__ offw, const float* __restrict__ c1w,
            const float* __restrict__ c2w) {
  const int fid = blockIdx.x * 256 + threadIdx.x;
  if (blockIdx.x == 0) g_st[threadIdx.x] = 0.f;
  __hip_bfloat16* Wo = (__hip_bfloat16*)(g_ws + OFF_WO);
  __hip_bfloat16* W1 = (__hip_bfloat16*)(g_ws + OFF_W1);
  __hip_bfloat16* W2 = (__hip_bfloat16*)(g_ws + OFF_W2);
  if (fid < 294912) {            // Wo: (tap*256+oc)*128+ic
    int ic = fid & 127, rest = fid >> 7, oc = rest & 255, tap = rest >> 8;
    Wo[fid] = __float2bfloat16(offw[(oc * 128 + ic) * 9 + tap]);
  } else if (fid < 368640) {     // W1: (tap*64+oc)*128+ic
    int l = fid - 294912;
    int ic = l & 127, rest = l >> 7, oc = rest & 63, tap = rest >> 6;
    W1[l] = __float2bfloat16(c1w[(oc * 128 + ic) * 9 + tap]);
  } else if (fid < 405504) {     // W2: (tap*64+oc)*64+ic
    int l = fid - 368640;
    int ic = l & 63, rest = l >> 6, oc = rest & 63, tap = rest >> 6;
    W2[l] = __float2bfloat16(c2w[(oc * 64 + ic) * 9 + tap]);
  } else {
    int u = fid - 405504;
    if (u < 82432) halo_zero((short*)(g_ws + OFF_XCAT), 128, 4, u);
    else if (u < 164864) halo_zero((short*)(g_ws + OFF_XD), 128, 4, u - 82432);
    else halo_zero((short*)(g_ws + OFF_H1), 64, 3, u - 164864);
  }
}

// ---------- xpose: x2 NCHW f32 -> padded xcat NHWC bf16 lower 64 channels ----------
__global__ __launch_bounds__(256)
void k_xpose(const float* __restrict__ x2) {
  __shared__ short T[256][72];
  const int t = threadIdx.x;
  const int h = blockIdx.x & 255, b = blockIdx.x >> 8;
  const float* src = x2 + (size_t)(b * 64) * 65536 + h * 256;
  for (int rep = 0; rep < 64; ++rep) {
    int flat = rep * 256 + t, c = flat >> 8, w = flat & 255;
    T[w][c] = f2b(src[(size_t)c * 65536 + w]);
  }
  __syncthreads();
  short* xcat = (short*)(g_ws + OFF_XCAT) +
                (((size_t)(b * 258) + h + 1) * XROW + 1) * 128;
  for (int rep = 0; rep < 8; ++rep) {
    int unit = rep * 256 + t;  // w*8+cg
    int w = unit >> 3, cg = unit & 7;
    *(short8*)(xcat + (size_t)w * 128 + cg * 8) = *(short8*)(&T[w][cg * 8]);
  }
}

// ---------- upmfma: convT(2x2,s2) via 4 parity GEMMs -> padded xcat upper + XPU planar ----------
__global__ __launch_bounds__(256)
void k_upmfma(const float* __restrict__ x1, const float* __restrict__ up_w,
              const float* __restrict__ up_b) {
  __shared__ short W4[4][64][66];   // [k*2+l][o][i]
  __shared__ short X[64][68];       // [ws][i]
  __shared__ short U[2][128][66];   // [k][wl][o]
  __shared__ float BS[64];
  const int t = threadIdx.x;
  const int half = blockIdx.x & 1, hs = (blockIdx.x >> 1) & 127, b = blockIdx.x >> 8;
  for (int rep = 0; rep < 64; ++rep) {
    int flat = rep * 256 + t;
    int i = flat >> 8, rest = flat & 255, o = rest >> 2, kl = rest & 3;
    W4[kl][o][i] = f2b(up_w[flat]);
  }
  if (t < 64) BS[t] = up_b[t];
  const float* x1b = x1 + (size_t)(b * 64) * 16384 + hs * 128 + half * 64;
  for (int rep = 0; rep < 16; ++rep) {
    int flat = rep * 256 + t;
    int i = flat >> 6, ws = flat & 63;
    X[ws][i] = f2b(x1b[(size_t)i * 16384 + ws]);
  }
  __syncthreads();
  const int wv = t >> 6, lane = t & 63, l15 = lane & 15, quad = lane >> 4;
  short8 bf[2];
#pragma unroll
  for (int ks = 0; ks < 2; ++ks)
    bf[ks] = *(const short8*)(&X[wv * 16 + l15][ks * 32 + quad * 8]);
#pragma unroll
  for (int combo = 0; combo < 4; ++combo) {
    const int k = combo >> 1, l = combo & 1;
    f32x4 acc[4] = {};
#pragma unroll
    for (int nt = 0; nt < 4; ++nt)
#pragma unroll
      for (int ks = 0; ks < 2; ++ks) {
        short8 af = *(const short8*)(&W4[combo][nt * 16 + l15][ks * 32 + quad * 8]);
        acc[nt] = __builtin_amdgcn_mfma_f32_16x16x32_bf16(af, bf[ks], acc[nt], 0, 0, 0);
      }
    const int wl = 2 * (wv * 16 + l15) + l;
#pragma unroll
    for (int nt = 0; nt < 4; ++nt) {
      short4v s;
#pragma unroll
      for (int r = 0; r < 4; ++r) s[r] = f2b(acc[nt][r] + BS[nt * 16 + quad * 4 + r]);
      *(short4v*)(&U[k][wl][nt * 16 + quad * 4]) = s;
    }
  }
  __syncthreads();
  short* xcat = (short*)(g_ws + OFF_XCAT);
  short* xpu = (short*)(g_ws + OFF_XPU);
  for (int rep = 0; rep < 8; ++rep) {
    int unit = rep * 256 + t;
    int k = unit >> 10, wl = (unit >> 3) & 127, cg = unit & 7;
    int h = 2 * hs + k, w = half * 128 + wl;
    *(short8*)(xcat + (((size_t)(b * 258) + h + 1) * XROW + w + 1) * 128 + 64 + cg * 8) =
        *(short8*)(&U[k][wl][cg * 8]);
  }
  for (int rep = 0; rep < 8; ++rep) {
    int unit = rep * 256 + t;
    int o = unit >> 5, k = (unit >> 4) & 1, wg = unit & 15;
    int h = 2 * hs + k;
    short8 v;
#pragma unroll
    for (int j = 0; j < 8; ++j) v[j] = U[k][wg * 8 + j][o];
    *(short8*)(xpu + (size_t)(b * 64 + o) * 65536 + h * 256 + half * 128 + wg * 8) = v;
  }
}

// ---------- offconv: BOTH-operands-in-LDS implicit GEMM, 256px x 256oc (R8, ~87us) ----------
__global__ __launch_bounds__(512, 2)
void k_offconv() {
  __shared__ short Bs[3 * 264 * 64];   // 101376 B
  __shared__ short As0[256 * 32];      // 16384 B
  __shared__ short As1[256 * 32];      // 16384 B
  const short* X = (const short*)(g_ws + OFF_XCAT);
  const __hip_bfloat16* W = (const __hip_bfloat16*)(g_ws + OFF_WO);
  const int t = threadIdx.x;
  const int vb = (int)((blockIdx.x & 7) * 64 + (blockIdx.x >> 3));  // bijective, 512%8==0
  const int h = vb & 255, b = vb >> 8;
  const int wid = t >> 6, lane = t & 63, l15 = lane & 15, quad = lane >> 4;
  const int ocbase = (wid & 1) * 128;
  const int pxb = (wid >> 1) * 64;
  const int lpx = lane >> 3, lcg = lane & 7;
  const short* bsrc = X + (((size_t)(b * 258) + h) * XROW + lpx) * 128 + (lcg ^ (lpx & 7)) * 8;
  const int loc = lane >> 2, lcg4 = lane & 3;
  const __hip_bfloat16* asrc = W + (size_t)loc * 128 + (lcg4 ^ ((loc + (loc >> 2)) & 3)) * 8;
  const int ax = (quad ^ ((l15 + (l15 >> 2)) & 3)) << 3;  // shorts
  const int abase = (ocbase + l15) * 32 + ax;
  f32x4 acc[8][4] = {};

#define STAGE_A(TAP, ICS, P, APTR)                                                  \
  {                                                                                 \
    _Pragma("unroll")                                                               \
    for (int k = 0; k < 2; ++k) {                                                   \
      int u = wid * 2 + k;                                                          \
      gload_lds16(asrc + ((size_t)(TAP) * 256 + u * 16) * 128 + (P) * 64 + (ICS) * 32, \
                  &APTR[u * 512]);                                                  \
    }                                                                               \
  }

  for (int p = 0; p < 2; ++p) {
    if (p) __syncthreads();
    for (int u = wid; u < 99; u += 8) {
      int r = u / 33, g = u - r * 33;
      gload_lds16(bsrc + (size_t)r * XRSH + g * 1024 + p * 64, &Bs[(r * 264 + g * 8) * 64]);
    }
    STAGE_A(0, 0, p, As0);
    STAGE_A(0, 1, p, As1);
    __syncthreads();
    for (int tap = 0; tap < 9; ++tap) {
      const int ky = tap / 3, kx = tap - 3 * ky;
      const short* srow = &Bs[(ky * 264 + pxb + l15 + kx) * 64];
      const int sx = ((l15 + kx) & 7) << 3;
      {  // ics = 0
        short8 a[8], bf[4];
#pragma unroll
        for (int ot = 0; ot < 8; ++ot) a[ot] = *(const short8*)(As0 + abase + ot * 512);
#pragma unroll
        for (int pt = 0; pt < 4; ++pt)
          bf[pt] = *(const short8*)(srow + pt * 1024 + ((quad * 8) ^ sx));
        __syncthreads();
        if (tap < 8) STAGE_A(tap + 1, 0, p, As0);
#pragma unroll
        for (int ot = 0; ot < 8; ++ot)
#pragma unroll
          for (int pt = 0; pt < 4; ++pt)
            acc[ot][pt] = __builtin_amdgcn_mfma_f32_16x16x32_bf16(a[ot], bf[pt], acc[ot][pt], 0, 0, 0);
      }
      {  // ics = 1
        short8 a[8], bf[4];
#pragma unroll
        for (int ot = 0; ot < 8; ++ot) a[ot] = *(const short8*)(As1 + abase + ot * 512);
#pragma unroll
        for (int pt = 0; pt < 4; ++pt)
          bf[pt] = *(const short8*)(srow + pt * 1024 + ((32 + quad * 8) ^ sx));
        __syncthreads();
        if (tap < 8) STAGE_A(tap + 1, 1, p, As1);
#pragma unroll
        for (int ot = 0; ot < 8; ++ot)
#pragma unroll
          for (int pt = 0; pt < 4; ++pt)
            acc[ot][pt] = __builtin_amdgcn_mfma_f32_16x16x32_bf16(a[ot], bf[pt], acc[ot][pt], 0, 0, 0);
      }
    }
  }
  __hip_bfloat16* out = (__hip_bfloat16*)(g_ws + OFF_OFF);  // NCHW (B,256,256,256)
#pragma unroll
  for (int ot = 0; ot < 8; ++ot)
#pragma unroll
    for (int pt = 0; pt < 4; ++pt)
#pragma unroll
      for (int r = 0; r < 4; ++r) {
        int oc = ocbase + ot * 16 + quad * 4 + r;
        int px = pxb + pt * 16 + l15;
        out[(((size_t)(b * 256 + oc)) * 256 + h) * 256 + px] =
            __float2bfloat16(acc[ot][pt][r]);
      }
#undef STAGE_A
}

// ---------- k_conv: LDS-staged implicit-GEMM 3x3 conv (OC=64) + bias + fused BN stats ----------
template <int IC, int SO>
__global__ __launch_bounds__(256, 2)
void k_conv(size_t xoff, size_t woff, const float* __restrict__ bias, size_t ooff) {
  __shared__ short Bs[3 * 272 * 32];   // 52224 B
  __shared__ short As[2 * 2048];       // 8192 B (two 64oc x 32ch tiles)
  __shared__ float SB[128];
  const short* X = (const short*)(g_ws + xoff);
  const __hip_bfloat16* W = (const __hip_bfloat16*)(g_ws + woff);
  const int t = threadIdx.x;
  const int vb = (int)((blockIdx.x & 7) * 64 + (blockIdx.x >> 3));  // bijective, 512%8==0
  const int h = vb & 255, b = vb >> 8;
  const int wid = t >> 6, lane = t & 63, l15 = lane & 15, quad = lane >> 4;
  const int pxb = wid * 64;
  if (t < 128) SB[t] = 0.f;
  const int lpx = lane >> 2, lc = lane & 3;
  const int fl = (lpx + (lpx >> 2)) & 3;
  const short* bsrc = X + (((size_t)(b * 258) + h) * XROW + lpx) * IC + (lc ^ fl) * 8;
  const __hip_bfloat16* asrc = W + (size_t)lpx * IC + (lc ^ fl) * 8;
  const int aslot = (quad ^ ((l15 + (l15 >> 2)) & 3)) << 3;  // shorts
  f32x4 acc[4][4] = {};
  const int KP = IC / 32;
  for (int ph = 0; ph < KP; ++ph) {
    for (int u = wid; u < 51; u += 4) {      // B: 3 rows x 17 units of 16px x 32ch
      int r = u / 17, g = u - r * 17;
      gload_lds16(bsrc + ((size_t)r * XROW + g * 16) * IC + ph * 32,
                  &Bs[(r * 272 + g * 16) * 32]);
    }
    gload_lds16(asrc + (size_t)(wid * 16) * IC + ph * 32, &As[wid * 512]);  // tap 0 -> buf 0
    __syncthreads();          // drains own vmcnt -> Bs + As[0] ready for all
    for (int tap = 0; tap < 9; ++tap) {
      short* Ac = &As[(tap & 1) * 2048];
      short* An = &As[((tap & 1) ^ 1) * 2048];
      if (tap < 8)            // restage next tap into idle buffer (no reader yet)
        gload_lds16(asrc + ((size_t)((tap + 1) * 64) + wid * 16) * IC + ph * 32,
                    &An[wid * 512]);
      const int ky = tap / 3, kx = tap - 3 * ky;
      short8 a[4], bf[4];
#pragma unroll
      for (int ot = 0; ot < 4; ++ot)
        a[ot] = *(const short8*)(&Ac[(ot * 16 + l15) * 32 + aslot]);
      const int s = l15 + kx;
      const int bslot = (quad ^ ((s + (s >> 2)) & 3)) << 3;
#pragma unroll
      for (int pt = 0; pt < 4; ++pt)
        bf[pt] = *(const short8*)(&Bs[(ky * 272 + pxb + pt * 16 + s) * 32 + bslot]);
#pragma unroll
      for (int ot = 0; ot < 4; ++ot)
#pragma unroll
        for (int pt = 0; pt < 4; ++pt)
          acc[ot][pt] = __builtin_amdgcn_mfma_f32_16x16x32_bf16(a[ot], bf[pt], acc[ot][pt], 0, 0, 0);
      __syncthreads();        // own restage drained -> An ready for ALL waves
    }
  }
  // epilogue: bias + store NHWC + fused stats
  __hip_bfloat16* out = (__hip_bfloat16*)(g_ws + ooff);
#pragma unroll
  for (int ot = 0; ot < 4; ++ot) {
    const int oc0 = ot * 16 + quad * 4;
    float bv[4], sa[4] = {}, sa2[4] = {};
#pragma unroll
    for (int r = 0; r < 4; ++r) bv[r] = bias[oc0 + r];
#pragma unroll
    for (int pt = 0; pt < 4; ++pt) {
      const int px = pxb + pt * 16 + l15;
      short4v sv;
#pragma unroll
      for (int r = 0; r < 4; ++r) {
        float f = acc[ot][pt][r] + bv[r];
        sv[r] = f2b(f);
        sa[r] += f;
        sa2[r] = fmaf(f, f, sa2[r]);
      }
      *(short4v*)(out + ((((size_t)(b * 256) + h) * 256 + px) * 64 + oc0)) = sv;
    }
#pragma unroll
    for (int r = 0; r < 4; ++r) {
      float sv1 = sa[r], sv2 = sa2[r];
      for (int d = 1; d < 16; d <<= 1) {
        sv1 += __shfl_xor(sv1, d);
        sv2 += __shfl_xor(sv2, d);
      }
      if (l15 == 0) {
        atomicAdd(&SB[oc0 + r], sv1);
        atomicAdd(&SB[64 + oc0 + r], sv2);
      }
    }
  }
  __syncthreads();
  if (t < 128) atomicAdd(&g_st[SO + t], SB[t]);
}

// ---------- deform gather: channel-half per block -> PADDED xd ----------
__global__ __launch_bounds__(256, 4)
void k_gather(const float* __restrict__ x2) {
  __shared__ short G[256 * 66];   // 33792 B
  const __hip_bfloat16* off = (const __hip_bfloat16*)(g_ws + OFF_OFF);
  const __hip_bfloat16* xpu = (const __hip_bfloat16*)(g_ws + OFF_XPU);
  short* xd = (short*)(g_ws + OFF_XD);
  const int t = threadIdx.x;
  const int half = blockIdx.x & 1;
  const int hh = (blockIdx.x >> 1) & 255, b = blockIdx.x >> 9;
  const int hp = 2 * (hh & 127) + (t >> 7);
  const int w0e = 2 * (t & 127);
  const int chb = hh >> 7;
  const int c0 = half * 64;
  const float fh = (float)hh, fw = (float)t;
  const __hip_bfloat16* offb = off + ((size_t)(b * 256) * 256 + hp) * 256 + w0e +
                               (size_t)(2 * c0 + chb) * 65536;
  if (half == 0) {
    const float* x2b = x2 + (size_t)b * 64 * 65536;
    for (int g4 = 0; g4 < 16; ++g4) {
      unsigned ovv[4];
#pragma unroll
      for (int j = 0; j < 4; ++j)
        ovv[j] = *(const unsigned*)(offb + (size_t)(2 * (g4 * 4 + j)) * 65536);
#pragma unroll
      for (int j = 0; j < 4; ++j) {
        const int crel = g4 * 4 + j;
        unsigned ov = ovv[j];
        float oy = __uint_as_float((ov & 0xffffu) << 16);
        float ox = __uint_as_float((ov >> 16) << 16);
        float cy = fminf(fmaxf(oy + fh, 0.f), 255.f);
        float cx = fminf(fmaxf(ox + fw, 0.f), 255.f);
        float y0f = floorf(cy), x0f = floorf(cx);
        int y0 = (int)y0f, x0 = (int)x0f;
        int y1 = (int)ceilf(cy), x1 = (int)ceilf(cx);
        const float* pl = x2b + (size_t)crel * 65536;
        float v00 = pl[y0 * 256 + x0], v10 = pl[y1 * 256 + x0];
        float v01 = pl[y0 * 256 + x1], v11 = pl[y1 * 256 + x1];
        float wy = cy - y0f, wx = cx - x0f;
        float vt = v00 + (v10 - v00) * wy;
        float vb = v01 + (v11 - v01) * wy;
        G[t * 66 + crel] = f2b(vt + (vb - vt) * wx);
      }
    }
  } else {
    const __hip_bfloat16* xub = xpu + (size_t)b * 64 * 65536;
    for (int g4 = 0; g4 < 16; ++g4) {
      unsigned ovv[4];
#pragma unroll
      for (int j = 0; j < 4; ++j)
        ovv[j] = *(const unsigned*)(offb + (size_t)(2 * (g4 * 4 + j)) * 65536);
#pragma unroll
      for (int j = 0; j < 4; ++j) {
        const int crel = g4 * 4 + j;
        unsigned ov = ovv[j];
        float oy = __uint_as_float((ov & 0xffffu) << 16);
        float ox = __uint_as_float((ov >> 16) << 16);
        float cy = fminf(fmaxf(oy + fh, 0.f), 255.f);
        float cx = fminf(fmaxf(ox + fw, 0.f), 255.f);
        float y0f = floorf(cy), x0f = floorf(cx);
        int y0 = (int)y0f, x0 = (int)x0f;
        int y1 = (int)ceilf(cy), x1 = (int)ceilf(cx);
        const __hip_bfloat16* pl = xub + (size_t)crel * 65536;
        float v00 = b2f(pl[y0 * 256 + x0]), v10 = b2f(pl[y1 * 256 + x0]);
        float v01 = b2f(pl[y0 * 256 + x1]), v11 = b2f(pl[y1 * 256 + x1]);
        float wy = cy - y0f, wx = cx - x0f;
        float vt = v00 + (v10 - v00) * wy;
        float vb = v01 + (v11 - v01) * wy;
        G[t * 66 + crel] = f2b(vt + (vb - vt) * wx);
      }
    }
  }
  __syncthreads();
  const size_t dst = (((size_t)(b * 258) + hh + 1) * XROW + 1) * 128 + c0;
  for (int it = 0; it < 8; ++it) {
    int g = it * 256 + t;
    *(short8*)(xd + dst + (size_t)(g >> 3) * 128 + (g & 7) * 8) =
        *(short8*)(&G[(g >> 3) * 66 + (g & 7) * 8]);
  }
}

// ---------- BN apply + ReLU: c1o NHWC -> PADDED h1 NHWC bf16 (finstat folded) ----------
__global__ __launch_bounds__(256)
void k_bnrelu1(const float* __restrict__ g, const float* __restrict__ be) {
  __shared__ float A[64], Bc[64];
  const __hip_bfloat16* x = (const __hip_bfloat16*)(g_ws + OFF_C1O);
  short* o = (short*)(g_ws + OFF_H1);
  const int t = threadIdx.x;
  const int h = blockIdx.x & 255, b = blockIdx.x >> 8;
  if (t < 64) {
    float m = g_st[t] * (1.f / 131072.f);
    float v = g_st[64 + t] * (1.f / 131072.f) - m * m;
    float iv = rsqrtf(v + 1e-5f) * g[t];
    A[t] = iv;
    Bc[t] = be[t] - m * iv;
  }
  __syncthreads();
  const __hip_bfloat16* px = x + (((size_t)(b * 256) + h) * 256 + t) * 64;
  short* op = o + (((size_t)(b * 258) + h + 1) * XROW + t + 1) * 64;
#pragma unroll
  for (int cg = 0; cg < 8; ++cg) {
    short8 v = *(const short8*)(px + cg * 8);
    short8 r;
#pragma unroll
    for (int j = 0; j < 8; ++j) {
      int c = cg * 8 + j;
      r[j] = f2b(fmaxf(s2f(v[j]) * A[c] + Bc[c], 0.f));
    }
    *(short8*)(op + cg * 8) = r;
  }
}

// ---------- BN apply + ReLU + NHWC->NCHW f32 to d_out (finstat folded) ----------
__global__ __launch_bounds__(256)
void k_bnrelu2(const float* __restrict__ g, const float* __restrict__ be,
               float* __restrict__ dout) {
  __shared__ float T[64 * 257];
  __shared__ float A[64], Bc[64];
  const __hip_bfloat16* x = (const __hip_bfloat16*)(g_ws + OFF_C2O);
  const int t = threadIdx.x;
  const int h = blockIdx.x & 255, b = blockIdx.x >> 8;
  if (t < 64) {
    float m = g_st[128 + t] * (1.f / 131072.f);
    float v = g_st[192 + t] * (1.f / 131072.f) - m * m;
    float iv = rsqrtf(v + 1e-5f) * g[t];
    A[t] = iv;
    Bc[t] = be[t] - m * iv;
  }
  __syncthreads();
  const __hip_bfloat16* px = x + (((size_t)(b * 256) + h) * 256 + t) * 64;
#pragma unroll
  for (int cg = 0; cg < 8; ++cg) {
    short8 v = *(const short8*)(px + cg * 8);
#pragma unroll
    for (int j = 0; j < 8; ++j) {
      int c = cg * 8 + j;
      T[c * 257 + t] = fmaxf(s2f(v[j]) * A[c] + Bc[c], 0.f);
    }
  }
  __syncthreads();
  for (int rep = 0; rep < 64; ++rep) {
    int flat = rep * 256 + t, c = flat >> 8, w = flat & 255;
    dout[(((size_t)(b * 64 + c)) * 256 + h) * 256 + w] = T[c * 257 + w];
  }
}

extern "C" void kernel_launch(void* const* d_in, const int* in_sizes, int n_in,
                              void* d_out, int out_size, void* d_ws, size_t ws_size,
                              hipStream_t stream) {
  const bool ok = (n_in == 13) &&
                  in_sizes[0] == 2097152 && in_sizes[1] == 8388608 &&
                  in_sizes[2] == 16384 && in_sizes[3] == 64 &&
                  in_sizes[4] == 294912 && in_sizes[5] == 73728 &&
                  in_sizes[9] == 36864 && out_size == 8388608;
  if (!ok) { hipMemsetAsync(d_out, 0x46, (size_t)out_size * 2, stream); return; }

  const float* x1   = (const float*)d_in[0];
  const float* x2   = (const float*)d_in[1];
  const float* up_w = (const float*)d_in[2];
  const float* up_b = (const float*)d_in[3];
  const float* offw = (const float*)d_in[4];
  const float* c1w  = (const float*)d_in[5];
  const float* c1b  = (const float*)d_in[6];
  const float* g1   = (const float*)d_in[7];
  const float* b1   = (const float*)d_in[8];
  const float* c2w  = (const float*)d_in[9];
  const float* c2b  = (const float*)d_in[10];
  const float* g2   = (const float*)d_in[11];
  const float* b2   = (const float*)d_in[12];

  k_prep<<<2389, 256, 0, stream>>>(offw, c1w, c2w);
  k_xpose<<<512, 256, 0, stream>>>(x2);
  k_upmfma<<<512, 256, 0, stream>>>(x1, up_w, up_b);
  k_offconv<<<512, 512, 0, stream>>>();
  k_gather<<<1024, 256, 0, stream>>>(x2);
  k_conv<128, 0><<<512, 256, 0, stream>>>(OFF_XD, OFF_W1, c1b, OFF_C1O);
  k_bnrelu1<<<512, 256, 0, stream>>>(g1, b1);
  k_conv<64, 128><<<512, 256, 0, stream>>>(OFF_H1, OFF_W2, c2b, OFF_C2O);
  k_bnrelu2<<<512, 256, 0, stream>>>(g2, b2, (float*)d_out);

  (void)d_ws; (void)ws_size;
}

// Round 14
// 337.064 us; speedup vs baseline: 1.0599x; 1.0143x over previous
//
#include <hip/hip_runtime.h>
#include <hip/hip_bf16.h>

// Problem: B=2, Ccat=128, OUT=64, H=W=256, f32 in/out storage, bf16-grade 2% tol.
// Pipeline (9 launches) — R8 configuration + 2-tap-paired k_conv (isolated from
// R12, where it was bundled with the regressing launch-merge):
//   prep: weights -> [tap][oc][ic] bf16; zero stats; zero ALL padded halos
//   xpose: x2 NCHW -> padded xcat NHWC lower 64ch
//   upmfma: convT2x2 (MFMA, 4 parity GEMMs) -> padded xcat upper 64ch + planar XPU
//   offconv: both-operands-in-LDS implicit GEMM 128->256, 256px x 256oc,
//            512 thr / 8 waves, 32 MFMA/barrier (~83us, MfmaUtil ~38%)
//   gather: bilinear deform -> PADDED xd NHWC bf16 (4 blocks/CU, 4-deep MLP)
//   conv1 = k_conv<128,0>: LDS implicit GEMM, 2-TAP pairing (32 MFMA/barrier),
//           + bias + fused BN-stats
//   bnrelu1: BN(from raw sums)+ReLU -> PADDED h1
//   conv2 = k_conv<64,128>: same
//   bnrelu2: BN+ReLU + NHWC->NCHW f32 -> d_out
// SESSION LESSONS (R9-R12, falsified alternatives):
//   - offconv reshape: 128x128@3blk=91us; 128x256@2blk(256thr)=106us(+spill);
//     the 256x256@512thr shape is the plateau optimum.
//   - gather 8-deep MLP: neutral vs 4-deep.
//   - merging prep/xpose/upmfma into one launch: REGRESSION — launch gaps drain
//     ~70MB dirty L2 (xcat+XPU) before offconv; merged, that writeback lands
//     inside offconv's window (83->103us, WRITE +8MB).
// Padded buffers: (B, 258, 264, C) bf16, data at [1..256][1..256], halos zeroed
// by prep -> conv staging needs no bounds checks.
// REGISTER BUDGET (R1/R3/R10): acc[8][4]=128 regs needs cap 256 AND the
// 512-thread shape (256-thread variants partially spill: +25MB WRITE).
// BARRIER-SPACING INVARIANT (R7): a gload_lds restage is visible to OTHER waves
// only after a __syncthreads() that FOLLOWS the issue. Ping-pong buffers.
// g_ws: xcat 0..36Mi | off 36..100Mi | xd(pad) 100..134Mi | c1o 134..150Mi |
//  h1(pad) 150..168Mi | c2o 168..184Mi | Wo/W1/W2 184Mi..+811008 | XPU 185..201Mi

typedef short short8 __attribute__((ext_vector_type(8)));
typedef short short4v __attribute__((ext_vector_type(4)));
typedef float f32x4 __attribute__((ext_vector_type(4)));

__device__ unsigned char g_ws[201u << 20] __attribute__((aligned(256)));
__device__ float g_st[256];

#define OFF_XCAT 0u
#define OFF_OFF  (36u << 20)
#define OFF_XD   (100u << 20)
#define OFF_C1O  (134u << 20)
#define OFF_H1   (150u << 20)
#define OFF_C2O  (168u << 20)
#define OFF_WO   (184u << 20)
#define OFF_W1   ((184u << 20) + 589824u)
#define OFF_W2   ((184u << 20) + 737280u)
#define OFF_XPU  (185u << 20)

// padded buffer geometry
#define XROW 264            // px per padded row
#define XRSH (XROW * 128)   // shorts per padded xcat row

__device__ __forceinline__ float b2f(__hip_bfloat16 v) { return __bfloat162float(v); }
__device__ __forceinline__ short f2b(float v) {
  __hip_bfloat16 h = __float2bfloat16(v); short s; __builtin_memcpy(&s, &h, 2); return s;
}
__device__ __forceinline__ float s2f(short s) {
  __hip_bfloat16 h; __builtin_memcpy(&h, &s, 2); return __bfloat162float(h);
}
__device__ __forceinline__ void gload_lds16(const void* g, void* l) {
  __builtin_amdgcn_global_load_lds(
      (const __attribute__((address_space(1))) void*)g,
      (__attribute__((address_space(3))) void*)l, 16, 0, 0);
}

// ---------- prep: weight transforms + zero stats + zero padded halos ----------
__device__ __forceinline__ void halo_zero(short* base, int C, int cshift, int u) {
  const int cg = u & ((1 << cshift) - 1);
  const int rest = u >> cshift;
  const int p = rest % 2576, b = rest / 2576;
  int row, col;
  if (p < 264) { row = 0; col = p; }
  else if (p < 528) { row = 257; col = p - 264; }
  else { int q = p - 528; row = 1 + (q >> 3); int cs = q & 7; col = cs ? 256 + cs : 0; }
  short8 z = {};
  *(short8*)(base + (((size_t)(b * 258) + row) * XROW + col) * C + cg * 8) = z;
}

__global__ __launch_bounds__(256)
void k_prep(const float* __restrict__ offw, const float* __restrict__ c1w,
            const float* __restrict__ c2w) {
  const int fid = blockIdx.x * 256 + threadIdx.x;
  if (blockIdx.x == 0) g_st[threadIdx.x] = 0.f;
  __hip_bfloat16* Wo = (__hip_bfloat16*)(g_ws + OFF_WO);
  __hip_bfloat16* W1 = (__hip_bfloat16*)(g_ws + OFF_W1);
  __hip_bfloat16* W2 = (__hip_bfloat16*)(g_ws + OFF_W2);
  if (fid < 294912) {            // Wo: (tap*256+oc)*128+ic
    int ic = fid & 127, rest = fid >> 7, oc = rest & 255, tap = rest >> 8;
    Wo[fid] = __float2bfloat16(offw[(oc * 128 + ic) * 9 + tap]);
  } else if (fid < 368640) {     // W1: (tap*64+oc)*128+ic
    int l = fid - 294912;
    int ic = l & 127, rest = l >> 7, oc = rest & 63, tap = rest >> 6;
    W1[l] = __float2bfloat16(c1w[(oc * 128 + ic) * 9 + tap]);
  } else if (fid < 405504) {     // W2: (tap*64+oc)*64+ic
    int l = fid - 368640;
    int ic = l & 63, rest = l >> 6, oc = rest & 63, tap = rest >> 6;
    W2[l] = __float2bfloat16(c2w[(oc * 64 + ic) * 9 + tap]);
  } else {
    int u = fid - 405504;
    if (u < 82432) halo_zero((short*)(g_ws + OFF_XCAT), 128, 4, u);
    else if (u < 164864) halo_zero((short*)(g_ws + OFF_XD), 128, 4, u - 82432);
    else halo_zero((short*)(g_ws + OFF_H1), 64, 3, u - 164864);
  }
}

// ---------- xpose: x2 NCHW f32 -> padded xcat NHWC bf16 lower 64 channels ----------
__global__ __launch_bounds__(256)
void k_xpose(const float* __restrict__ x2) {
  __shared__ short T[256][72];
  const int t = threadIdx.x;
  const int h = blockIdx.x & 255, b = blockIdx.x >> 8;
  const float* src = x2 + (size_t)(b * 64) * 65536 + h * 256;
  for (int rep = 0; rep < 64; ++rep) {
    int flat = rep * 256 + t, c = flat >> 8, w = flat & 255;
    T[w][c] = f2b(src[(size_t)c * 65536 + w]);
  }
  __syncthreads();
  short* xcat = (short*)(g_ws + OFF_XCAT) +
                (((size_t)(b * 258) + h + 1) * XROW + 1) * 128;
  for (int rep = 0; rep < 8; ++rep) {
    int unit = rep * 256 + t;  // w*8+cg
    int w = unit >> 3, cg = unit & 7;
    *(short8*)(xcat + (size_t)w * 128 + cg * 8) = *(short8*)(&T[w][cg * 8]);
  }
}

// ---------- upmfma: convT(2x2,s2) via 4 parity GEMMs -> padded xcat upper + XPU planar ----------
__global__ __launch_bounds__(256)
void k_upmfma(const float* __restrict__ x1, const float* __restrict__ up_w,
              const float* __restrict__ up_b) {
  __shared__ short W4[4][64][66];   // [k*2+l][o][i]
  __shared__ short X[64][68];       // [ws][i]
  __shared__ short U[2][128][66];   // [k][wl][o]
  __shared__ float BS[64];
  const int t = threadIdx.x;
  const int half = blockIdx.x & 1, hs = (blockIdx.x >> 1) & 127, b = blockIdx.x >> 8;
  for (int rep = 0; rep < 64; ++rep) {
    int flat = rep * 256 + t;
    int i = flat >> 8, rest = flat & 255, o = rest >> 2, kl = rest & 3;
    W4[kl][o][i] = f2b(up_w[flat]);
  }
  if (t < 64) BS[t] = up_b[t];
  const float* x1b = x1 + (size_t)(b * 64) * 16384 + hs * 128 + half * 64;
  for (int rep = 0; rep < 16; ++rep) {
    int flat = rep * 256 + t;
    int i = flat >> 6, ws = flat & 63;
    X[ws][i] = f2b(x1b[(size_t)i * 16384 + ws]);
  }
  __syncthreads();
  const int wv = t >> 6, lane = t & 63, l15 = lane & 15, quad = lane >> 4;
  short8 bf[2];
#pragma unroll
  for (int ks = 0; ks < 2; ++ks)
    bf[ks] = *(const short8*)(&X[wv * 16 + l15][ks * 32 + quad * 8]);
#pragma unroll
  for (int combo = 0; combo < 4; ++combo) {
    const int k = combo >> 1, l = combo & 1;
    f32x4 acc[4] = {};
#pragma unroll
    for (int nt = 0; nt < 4; ++nt)
#pragma unroll
      for (int ks = 0; ks < 2; ++ks) {
        short8 af = *(const short8*)(&W4[combo][nt * 16 + l15][ks * 32 + quad * 8]);
        acc[nt] = __builtin_amdgcn_mfma_f32_16x16x32_bf16(af, bf[ks], acc[nt], 0, 0, 0);
      }
    const int wl = 2 * (wv * 16 + l15) + l;
#pragma unroll
    for (int nt = 0; nt < 4; ++nt) {
      short4v s;
#pragma unroll
      for (int r = 0; r < 4; ++r) s[r] = f2b(acc[nt][r] + BS[nt * 16 + quad * 4 + r]);
      *(short4v*)(&U[k][wl][nt * 16 + quad * 4]) = s;
    }
  }
  __syncthreads();
  short* xcat = (short*)(g_ws + OFF_XCAT);
  short* xpu = (short*)(g_ws + OFF_XPU);
  for (int rep = 0; rep < 8; ++rep) {
    int unit = rep * 256 + t;
    int k = unit >> 10, wl = (unit >> 3) & 127, cg = unit & 7;
    int h = 2 * hs + k, w = half * 128 + wl;
    *(short8*)(xcat + (((size_t)(b * 258) + h + 1) * XROW + w + 1) * 128 + 64 + cg * 8) =
        *(short8*)(&U[k][wl][cg * 8]);
  }
  for (int rep = 0; rep < 8; ++rep) {
    int unit = rep * 256 + t;
    int o = unit >> 5, k = (unit >> 4) & 1, wg = unit & 15;
    int h = 2 * hs + k;
    short8 v;
#pragma unroll
    for (int j = 0; j < 8; ++j) v[j] = U[k][wg * 8 + j][o];
    *(short8*)(xpu + (size_t)(b * 64 + o) * 65536 + h * 256 + half * 128 + wg * 8) = v;
  }
}

// ---------- offconv: BOTH-operands-in-LDS implicit GEMM, 256px x 256oc (R8, ~83us) ----------
__global__ __launch_bounds__(512, 2)
void k_offconv() {
  __shared__ short Bs[3 * 264 * 64];   // 101376 B
  __shared__ short As0[256 * 32];      // 16384 B
  __shared__ short As1[256 * 32];      // 16384 B
  const short* X = (const short*)(g_ws + OFF_XCAT);
  const __hip_bfloat16* W = (const __hip_bfloat16*)(g_ws + OFF_WO);
  const int t = threadIdx.x;
  const int vb = (int)((blockIdx.x & 7) * 64 + (blockIdx.x >> 3));  // bijective, 512%8==0
  const int h = vb & 255, b = vb >> 8;
  const int wid = t >> 6, lane = t & 63, l15 = lane & 15, quad = lane >> 4;
  const int ocbase = (wid & 1) * 128;
  const int pxb = (wid >> 1) * 64;
  const int lpx = lane >> 3, lcg = lane & 7;
  const short* bsrc = X + (((size_t)(b * 258) + h) * XROW + lpx) * 128 + (lcg ^ (lpx & 7)) * 8;
  const int loc = lane >> 2, lcg4 = lane & 3;
  const __hip_bfloat16* asrc = W + (size_t)loc * 128 + (lcg4 ^ ((loc + (loc >> 2)) & 3)) * 8;
  const int ax = (quad ^ ((l15 + (l15 >> 2)) & 3)) << 3;  // shorts
  const int abase = (ocbase + l15) * 32 + ax;
  f32x4 acc[8][4] = {};

#define STAGE_A(TAP, ICS, P, APTR)                                                  \
  {                                                                                 \
    _Pragma("unroll")                                                               \
    for (int k = 0; k < 2; ++k) {                                                   \
      int u = wid * 2 + k;                                                          \
      gload_lds16(asrc + ((size_t)(TAP) * 256 + u * 16) * 128 + (P) * 64 + (ICS) * 32, \
                  &APTR[u * 512]);                                                  \
    }                                                                               \
  }

  for (int p = 0; p < 2; ++p) {
    if (p) __syncthreads();
    for (int u = wid; u < 99; u += 8) {
      int r = u / 33, g = u - r * 33;
      gload_lds16(bsrc + (size_t)r * XRSH + g * 1024 + p * 64, &Bs[(r * 264 + g * 8) * 64]);
    }
    STAGE_A(0, 0, p, As0);
    STAGE_A(0, 1, p, As1);
    __syncthreads();
    for (int tap = 0; tap < 9; ++tap) {
      const int ky = tap / 3, kx = tap - 3 * ky;
      const short* srow = &Bs[(ky * 264 + pxb + l15 + kx) * 64];
      const int sx = ((l15 + kx) & 7) << 3;
      {  // ics = 0
        short8 a[8], bf[4];
#pragma unroll
        for (int ot = 0; ot < 8; ++ot) a[ot] = *(const short8*)(As0 + abase + ot * 512);
#pragma unroll
        for (int pt = 0; pt < 4; ++pt)
          bf[pt] = *(const short8*)(srow + pt * 1024 + ((quad * 8) ^ sx));
        __syncthreads();
        if (tap < 8) STAGE_A(tap + 1, 0, p, As0);
#pragma unroll
        for (int ot = 0; ot < 8; ++ot)
#pragma unroll
          for (int pt = 0; pt < 4; ++pt)
            acc[ot][pt] = __builtin_amdgcn_mfma_f32_16x16x32_bf16(a[ot], bf[pt], acc[ot][pt], 0, 0, 0);
      }
      {  // ics = 1
        short8 a[8], bf[4];
#pragma unroll
        for (int ot = 0; ot < 8; ++ot) a[ot] = *(const short8*)(As1 + abase + ot * 512);
#pragma unroll
        for (int pt = 0; pt < 4; ++pt)
          bf[pt] = *(const short8*)(srow + pt * 1024 + ((32 + quad * 8) ^ sx));
        __syncthreads();
        if (tap < 8) STAGE_A(tap + 1, 1, p, As1);
#pragma unroll
        for (int ot = 0; ot < 8; ++ot)
#pragma unroll
          for (int pt = 0; pt < 4; ++pt)
            acc[ot][pt] = __builtin_amdgcn_mfma_f32_16x16x32_bf16(a[ot], bf[pt], acc[ot][pt], 0, 0, 0);
      }
    }
  }
  __hip_bfloat16* out = (__hip_bfloat16*)(g_ws + OFF_OFF);  // NCHW (B,256,256,256)
#pragma unroll
  for (int ot = 0; ot < 8; ++ot)
#pragma unroll
    for (int pt = 0; pt < 4; ++pt)
#pragma unroll
      for (int r = 0; r < 4; ++r) {
        int oc = ocbase + ot * 16 + quad * 4 + r;
        int px = pxb + pt * 16 + l15;
        out[(((size_t)(b * 256 + oc)) * 256 + h) * 256 + px] =
            __float2bfloat16(acc[ot][pt][r]);
      }
#undef STAGE_A
}

// ---------- k_conv: LDS implicit-GEMM 3x3 conv (OC=64), 2-TAP pairing, + bias + stats ----------
// Per barrier interval (R9 lesson: 32 MFMA/barrier): stage next TAP PAIR into
// idle ping-pong buffer -> read 2 taps' A+B -> 32 MFMA -> barrier.
// Pairs: {0,1}{2,3}{4,5}{6,7}{8}. As buffers 2x4096 shorts (2 taps each).
// LDS 69.1KB -> 2 blocks/CU. R7 invariant holds (stage before barrier, reads
// of that buffer only after it). Correctness-verified in R12 (absmax 0.03125).
template <int IC, int SO>
__global__ __launch_bounds__(256, 2)
void k_conv(size_t xoff, size_t woff, const float* __restrict__ bias, size_t ooff) {
  __shared__ short Bs[3 * 272 * 32];   // 52224 B
  __shared__ short As[2][4096];        // 16384 B (each: 2 taps x 64oc x 32ch)
  __shared__ float SB[128];
  const short* X = (const short*)(g_ws + xoff);
  const __hip_bfloat16* W = (const __hip_bfloat16*)(g_ws + woff);
  const int t = threadIdx.x;
  const int vb = (int)((blockIdx.x & 7) * 64 + (blockIdx.x >> 3));  // bijective, 512%8==0
  const int h = vb & 255, b = vb >> 8;
  const int wid = t >> 6, lane = t & 63, l15 = lane & 15, quad = lane >> 4;
  const int pxb = wid * 64;
  if (t < 128) SB[t] = 0.f;
  const int lpx = lane >> 2, lc = lane & 3;
  const int fl = (lpx + (lpx >> 2)) & 3;
  const short* bsrc = X + (((size_t)(b * 258) + h) * XROW + lpx) * IC + (lc ^ fl) * 8;
  const __hip_bfloat16* asrc = W + (size_t)lpx * IC + (lc ^ fl) * 8;
  const int aslot = (quad ^ ((l15 + (l15 >> 2)) & 3)) << 3;  // shorts
  f32x4 acc[4][4] = {};
  const int KP = IC / 32;
  for (int ph = 0; ph < KP; ++ph) {
    for (int u = wid; u < 51; u += 4) {      // B: 3 rows x 17 units of 16px x 32ch
      int r = u / 17, g = u - r * 17;
      gload_lds16(bsrc + ((size_t)r * XROW + g * 16) * IC + ph * 32,
                  &Bs[(r * 272 + g * 16) * 32]);
    }
#pragma unroll
    for (int k = 0; k < 2; ++k) {            // pair {0,1} -> As[0]: 8 units of 16oc
      int u = wid * 2 + k;                   // u: tap=(u>>2), ocu=(u&3)
      gload_lds16(asrc + ((size_t)((u >> 2) * 64 + (u & 3) * 16)) * IC + ph * 32,
                  &As[0][u * 512]);
    }
    __syncthreads();          // own vmcnt drained -> Bs + As[0] ready for all
    for (int pr = 0; pr < 5; ++pr) {
      const short* cur = As[pr & 1];
      short* nxt = As[(pr & 1) ^ 1];
      if (pr < 4) {           // stage next pair (taps 2pr+2[,2pr+3]) into idle buf
        const int bt = 2 * pr + 2;
        const int nunits = (bt == 8) ? 4 : 8;
#pragma unroll
        for (int k = 0; k < 2; ++k) {
          int u = wid * 2 + k;
          if (u < nunits)
            gload_lds16(asrc + ((size_t)((bt + (u >> 2)) * 64 + (u & 3) * 16)) * IC + ph * 32,
                        &nxt[u * 512]);
        }
      }
      const int ntap = (pr == 4) ? 1 : 2;
      for (int tt = 0; tt < ntap; ++tt) {
        const int tap = 2 * pr + tt;
        const int ky = tap / 3, kx = tap - 3 * ky;
        short8 a[4], bf[4];
#pragma unroll
        for (int ot = 0; ot < 4; ++ot)
          a[ot] = *(const short8*)(&cur[tt * 2048 + (ot * 16 + l15) * 32 + aslot]);
        const int s = l15 + kx;
        const int bslot = (quad ^ ((s + (s >> 2)) & 3)) << 3;
#pragma unroll
        for (int pt = 0; pt < 4; ++pt)
          bf[pt] = *(const short8*)(&Bs[(ky * 272 + pxb + pt * 16 + s) * 32 + bslot]);
#pragma unroll
        for (int ot = 0; ot < 4; ++ot)
#pragma unroll
          for (int pt = 0; pt < 4; ++pt)
            acc[ot][pt] = __builtin_amdgcn_mfma_f32_16x16x32_bf16(a[ot], bf[pt], acc[ot][pt], 0, 0, 0);
      }
      __syncthreads();        // own restage drained -> nxt ready for ALL waves
    }
  }
  // epilogue: bias + store NHWC + fused stats
  __hip_bfloat16* out = (__hip_bfloat16*)(g_ws + ooff);
#pragma unroll
  for (int ot = 0; ot < 4; ++ot) {
    const int oc0 = ot * 16 + quad * 4;
    float bv[4], sa[4] = {}, sa2[4] = {};
#pragma unroll
    for (int r = 0; r < 4; ++r) bv[r] = bias[oc0 + r];
#pragma unroll
    for (int pt = 0; pt < 4; ++pt) {
      const int px = pxb + pt * 16 + l15;
      short4v sv;
#pragma unroll
      for (int r = 0; r < 4; ++r) {
        float f = acc[ot][pt][r] + bv[r];
        sv[r] = f2b(f);
        sa[r] += f;
        sa2[r] = fmaf(f, f, sa2[r]);
      }
      *(short4v*)(out + ((((size_t)(b * 256) + h) * 256 + px) * 64 + oc0)) = sv;
    }
#pragma unroll
    for (int r = 0; r < 4; ++r) {
      float sv1 = sa[r], sv2 = sa2[r];
      for (int d = 1; d < 16; d <<= 1) {
        sv1 += __shfl_xor(sv1, d);
        sv2 += __shfl_xor(sv2, d);
      }
      if (l15 == 0) {
        atomicAdd(&SB[oc0 + r], sv1);
        atomicAdd(&SB[64 + oc0 + r], sv2);
      }
    }
  }
  __syncthreads();
  if (t < 128) atomicAdd(&g_st[SO + t], SB[t]);
}

// ---------- deform gather: channel-half per block -> PADDED xd ----------
__global__ __launch_bounds__(256, 4)
void k_gather(const float* __restrict__ x2) {
  __shared__ short G[256 * 66];   // 33792 B
  const __hip_bfloat16* off = (const __hip_bfloat16*)(g_ws + OFF_OFF);
  const __hip_bfloat16* xpu = (const __hip_bfloat16*)(g_ws + OFF_XPU);
  short* xd = (short*)(g_ws + OFF_XD);
  const int t = threadIdx.x;
  const int half = blockIdx.x & 1;
  const int hh = (blockIdx.x >> 1) & 255, b = blockIdx.x >> 9;
  const int hp = 2 * (hh & 127) + (t >> 7);
  const int w0e = 2 * (t & 127);
  const int chb = hh >> 7;
  const int c0 = half * 64;
  const float fh = (float)hh, fw = (float)t;
  const __hip_bfloat16* offb = off + ((size_t)(b * 256) * 256 + hp) * 256 + w0e +
                               (size_t)(2 * c0 + chb) * 65536;
  if (half == 0) {
    const float* x2b = x2 + (size_t)b * 64 * 65536;
    for (int g4 = 0; g4 < 16; ++g4) {
      unsigned ovv[4];
#pragma unroll
      for (int j = 0; j < 4; ++j)
        ovv[j] = *(const unsigned*)(offb + (size_t)(2 * (g4 * 4 + j)) * 65536);
#pragma unroll
      for (int j = 0; j < 4; ++j) {
        const int crel = g4 * 4 + j;
        unsigned ov = ovv[j];
        float oy = __uint_as_float((ov & 0xffffu) << 16);
        float ox = __uint_as_float((ov >> 16) << 16);
        float cy = fminf(fmaxf(oy + fh, 0.f), 255.f);
        float cx = fminf(fmaxf(ox + fw, 0.f), 255.f);
        float y0f = floorf(cy), x0f = floorf(cx);
        int y0 = (int)y0f, x0 = (int)x0f;
        int y1 = (int)ceilf(cy), x1 = (int)ceilf(cx);
        const float* pl = x2b + (size_t)crel * 65536;
        float v00 = pl[y0 * 256 + x0], v10 = pl[y1 * 256 + x0];
        float v01 = pl[y0 * 256 + x1], v11 = pl[y1 * 256 + x1];
        float wy = cy - y0f, wx = cx - x0f;
        float vt = v00 + (v10 - v00) * wy;
        float vb = v01 + (v11 - v01) * wy;
        G[t * 66 + crel] = f2b(vt + (vb - vt) * wx);
      }
    }
  } else {
    const __hip_bfloat16* xub = xpu + (size_t)b * 64 * 65536;
    for (int g4 = 0; g4 < 16; ++g4) {
      unsigned ovv[4];
#pragma unroll
      for (int j = 0; j < 4; ++j)
        ovv[j] = *(const unsigned*)(offb + (size_t)(2 * (g4 * 4 + j)) * 65536);
#pragma unroll
      for (int j = 0; j < 4; ++j) {
        const int crel = g4 * 4 + j;
        unsigned ov = ovv[j];
        float oy = __uint_as_float((ov & 0xffffu) << 16);
        float ox = __uint_as_float((ov >> 16) << 16);
        float cy = fminf(fmaxf(oy + fh, 0.f), 255.f);
        float cx = fminf(fmaxf(ox + fw, 0.f), 255.f);
        float y0f = floorf(cy), x0f = floorf(cx);
        int y0 = (int)y0f, x0 = (int)x0f;
        int y1 = (int)ceilf(cy), x1 = (int)ceilf(cx);
        const __hip_bfloat16* pl = xub + (size_t)crel * 65536;
        float v00 = b2f(pl[y0 * 256 + x0]), v10 = b2f(pl[y1 * 256 + x0]);
        float v01 = b2f(pl[y0 * 256 + x1]), v11 = b2f(pl[y1 * 256 + x1]);
        float wy = cy - y0f, wx = cx - x0f;
        float vt = v00 + (v10 - v00) * wy;
        float vb = v01 + (v11 - v01) * wy;
        G[t * 66 + crel] = f2b(vt + (vb - vt) * wx);
      }
    }
  }
  __syncthreads();
  const size_t dst = (((size_t)(b * 258) + hh + 1) * XROW + 1) * 128 + c0;
  for (int it = 0; it < 8; ++it) {
    int g = it * 256 + t;
    *(short8*)(xd + dst + (size_t)(g >> 3) * 128 + (g & 7) * 8) =
        *(short8*)(&G[(g >> 3) * 66 + (g & 7) * 8]);
  }
}

// ---------- BN apply + ReLU: c1o NHWC -> PADDED h1 NHWC bf16 (finstat folded) ----------
__global__ __launch_bounds__(256)
void k_bnrelu1(const float* __restrict__ g, const float* __restrict__ be) {
  __shared__ float A[64], Bc[64];
  const __hip_bfloat16* x = (const __hip_bfloat16*)(g_ws + OFF_C1O);
  short* o = (short*)(g_ws + OFF_H1);
  const int t = threadIdx.x;
  const int h = blockIdx.x & 255, b = blockIdx.x >> 8;
  if (t < 64) {
    float m = g_st[t] * (1.f / 131072.f);
    float v = g_st[64 + t] * (1.f / 131072.f) - m * m;
    float iv = rsqrtf(v + 1e-5f) * g[t];
    A[t] = iv;
    Bc[t] = be[t] - m * iv;
  }
  __syncthreads();
  const __hip_bfloat16* px = x + (((size_t)(b * 256) + h) * 256 + t) * 64;
  short* op = o + (((size_t)(b * 258) + h + 1) * XROW + t + 1) * 64;
#pragma unroll
  for (int cg = 0; cg < 8; ++cg) {
    short8 v = *(const short8*)(px + cg * 8);
    short8 r;
#pragma unroll
    for (int j = 0; j < 8; ++j) {
      int c = cg * 8 + j;
      r[j] = f2b(fmaxf(s2f(v[j]) * A[c] + Bc[c], 0.f));
    }
    *(short8*)(op + cg * 8) = r;
  }
}

// ---------- BN apply + ReLU + NHWC->NCHW f32 to d_out (finstat folded) ----------
__global__ __launch_bounds__(256)
void k_bnrelu2(const float* __restrict__ g, const float* __restrict__ be,
               float* __restrict__ dout) {
  __shared__ float T[64 * 257];
  __shared__ float A[64], Bc[64];
  const __hip_bfloat16* x = (const __hip_bfloat16*)(g_ws + OFF_C2O);
  const int t = threadIdx.x;
  const int h = blockIdx.x & 255, b = blockIdx.x >> 8;
  if (t < 64) {
    float m = g_st[128 + t] * (1.f / 131072.f);
    float v = g_st[192 + t] * (1.f / 131072.f) - m * m;
    float iv = rsqrtf(v + 1e-5f) * g[t];
    A[t] = iv;
    Bc[t] = be[t] - m * iv;
  }
  __syncthreads();
  const __hip_bfloat16* px = x + (((size_t)(b * 256) + h) * 256 + t) * 64;
#pragma unroll
  for (int cg = 0; cg < 8; ++cg) {
    short8 v = *(const short8*)(px + cg * 8);
#pragma unroll
    for (int j = 0; j < 8; ++j) {
      int c = cg * 8 + j;
      T[c * 257 + t] = fmaxf(s2f(v[j]) * A[c] + Bc[c], 0.f);
    }
  }
  __syncthreads();
  for (int rep = 0; rep < 64; ++rep) {
    int flat = rep * 256 + t, c = flat >> 8, w = flat & 255;
    dout[(((size_t)(b * 64 + c)) * 256 + h) * 256 + w] = T[c * 257 + w];
  }
}

extern "C" void kernel_launch(void* const* d_in, const int* in_sizes, int n_in,
                              void* d_out, int out_size, void* d_ws, size_t ws_size,
                              hipStream_t stream) {
  const bool ok = (n_in == 13) &&
                  in_sizes[0] == 2097152 && in_sizes[1] == 8388608 &&
                  in_sizes[2] == 16384 && in_sizes[3] == 64 &&
                  in_sizes[4] == 294912 && in_sizes[5] == 73728 &&
                  in_sizes[9] == 36864 && out_size == 8388608;
  if (!ok) { hipMemsetAsync(d_out, 0x46, (size_t)out_size * 2, stream); return; }

  const float* x1   = (const float*)d_in[0];
  const float* x2   = (const float*)d_in[1];
  const float* up_w = (const float*)d_in[2];
  const float* up_b = (const float*)d_in[3];
  const float* offw = (const float*)d_in[4];
  const float* c1w  = (const float*)d_in[5];
  const float* c1b  = (const float*)d_in[6];
  const float* g1   = (const float*)d_in[7];
  const float* b1   = (const float*)d_in[8];
  const float* c2w  = (const float*)d_in[9];
  const float* c2b  = (const float*)d_in[10];
  const float* g2   = (const float*)d_in[11];
  const float* b2   = (const float*)d_in[12];

  k_prep<<<2389, 256, 0, stream>>>(offw, c1w, c2w);
  k_xpose<<<512, 256, 0, stream>>>(x2);
  k_upmfma<<<512, 256, 0, stream>>>(x1, up_w, up_b);
  k_offconv<<<512, 512, 0, stream>>>();
  k_gather<<<1024, 256, 0, stream>>>(x2);
  k_conv<128, 0><<<512, 256, 0, stream>>>(OFF_XD, OFF_W1, c1b, OFF_C1O);
  k_bnrelu1<<<512, 256, 0, stream>>>(g1, b1);
  k_conv<64, 128><<<512, 256, 0, stream>>>(OFF_H1, OFF_W2, c2b, OFF_C2O);
  k_bnrelu2<<<512, 256, 0, stream>>>(g2, b2, (float*)d_out);

  (void)d_ws; (void)ws_size;
}